// Round 1
// baseline (186.226 us; speedup 1.0000x reference)
//
#include <hip/hip_runtime.h>

// Problem constants (from reference setup_inputs).
constexpr int kB  = 16;
constexpr int kM  = 512;
constexpr int kS  = 32;
constexpr int kE  = 128;
constexpr int kV  = 32000;
constexpr int kVN = kV - 1;   // index kVN is the nil (zero) row

// -------------------------------------------------------------------------
// Kernel 1: story embeddings.
//   memory[b,m,e] = sum_s st_tab[stories[b,m,s]][e]*enc[s][e] + mem_bias[m][e]
//   output[b,m,e] = sum_s o_tab [stories[b,m,s]][e]*enc[s][e]
// enc[s][e] = 1 + (e-63)*(s-15)/1024  (exact f32 match of the numpy formula)
// One 128-thread group per (b,m) row; block of 256 handles 2 rows.
// -------------------------------------------------------------------------
__global__ __launch_bounds__(256) void embed_stories_kernel(
    const int*   __restrict__ stories,   // [B,M,S]
    const float* __restrict__ st_bias,   // [VN,E]
    const float* __restrict__ out_bias,  // [VN,E]
    const float* __restrict__ mem_bias,  // [M,E]
    float*       __restrict__ memory,    // [B,M,E]
    float*       __restrict__ output)    // [B,M,E]
{
    __shared__ int sidx[2][kS];
    const int t     = threadIdx.x;
    const int pair0 = blockIdx.x * 2;          // (b*M+m) of first row
    if (t < 64) {
        const int p = t >> 5, s = t & 31;
        sidx[p][s] = stories[(pair0 + p) * kS + s];
    }
    __syncthreads();
    const int p  = t >> 7;        // which of the 2 rows
    const int e  = t & 127;
    const int bm = pair0 + p;
    const int m  = bm & (kM - 1);

    float accm = mem_bias[m * kE + e];
    float acco = 0.0f;
    const float ef = (float)(e - 63);
    #pragma unroll
    for (int s = 0; s < kS; ++s) {
        const int idx   = sidx[p][s];
        const float enc = 1.0f + ef * (float)(s - 15) * (1.0f / 1024.0f);
        if (idx < kVN) {
            const size_t off = (size_t)idx * kE + e;
            accm = fmaf(st_bias[off],  enc, accm);
            acco = fmaf(out_bias[off], enc, acco);
        }
    }
    memory[(size_t)bm * kE + e] = accm;
    output[(size_t)bm * kE + e] = acco;
}

// -------------------------------------------------------------------------
// Kernel 2: query embedding + 3 attention hops, one block per batch b.
// 512 threads = 8 waves. Writes x[b,e] = relu(final pre-activation).
// -------------------------------------------------------------------------
__global__ __launch_bounds__(512) void hops_kernel(
    const int*   __restrict__ queries,  // [B,S]
    const float* __restrict__ q_bias,   // [VN,E]
    const float* __restrict__ memory,   // [B,M,E]
    const float* __restrict__ output,   // [B,M,E]
    const float* __restrict__ w_int,    // [E,E]
    const float* __restrict__ w_out,    // [E,E]
    float*       __restrict__ x)        // [B,E]
{
    __shared__ __align__(16) float q_s[kE];
    __shared__ float xbuf[kE];
    __shared__ float sc[kM];       // exp(score - max)
    __shared__ float part[4][kE];  // cross-group partial sums
    __shared__ float red[8];       // per-wave reduction scratch
    __shared__ int   qidx[kS];

    const int b = blockIdx.x;
    const int t = threadIdx.x;

    if (t < kS) qidx[t] = queries[b * kS + t];
    __syncthreads();

    // q[b,e] = sum_s q_tab[queries[b,s]][e] * enc[s][e]
    if (t < kE) {
        float acc = 0.0f;
        const float ef = (float)(t - 63);
        #pragma unroll
        for (int s = 0; s < kS; ++s) {
            const int idx   = qidx[s];
            const float enc = 1.0f + ef * (float)(s - 15) * (1.0f / 1024.0f);
            if (idx < kVN) acc = fmaf(q_bias[(size_t)idx * kE + t], enc, acc);
        }
        q_s[t] = acc;
    }
    __syncthreads();

    const float* memb = memory + (size_t)b * kM * kE;
    const float* outb = output + (size_t)b * kM * kE;
    const int g = t >> 7;      // group 0..3
    const int e = t & 127;

    for (int hop = 0; hop < 3; ++hop) {
        // --- scores: thread t handles m = t ---
        const float4* row = (const float4*)(memb + (size_t)t * kE);
        const float4* qv  = (const float4*)q_s;
        float sv = 0.0f;
        #pragma unroll
        for (int i = 0; i < kE / 4; ++i) {
            const float4 a = row[i], q4 = qv[i];
            sv += a.x * q4.x + a.y * q4.y + a.z * q4.z + a.w * q4.w;
        }
        // --- softmax over 512: max ---
        float v = sv;
        #pragma unroll
        for (int off = 32; off; off >>= 1) v = fmaxf(v, __shfl_down(v, off, 64));
        if ((t & 63) == 0) red[t >> 6] = v;
        __syncthreads();
        float mx = red[0];
        #pragma unroll
        for (int i = 1; i < 8; ++i) mx = fmaxf(mx, red[i]);
        const float ex = __expf(sv - mx);
        float sum = ex;
        #pragma unroll
        for (int off = 32; off; off >>= 1) sum += __shfl_down(sum, off, 64);
        __syncthreads();                       // done reading red (max)
        if ((t & 63) == 0) red[t >> 6] = sum;
        sc[t] = ex;
        __syncthreads();
        const float tot = red[0] + red[1] + red[2] + red[3] +
                          red[4] + red[5] + red[6] + red[7];
        const float inv = 1.0f / tot;

        // --- layer_out[e] = (sum_m ex[m]*output[b,m,e]) * inv ---
        float acc = 0.0f;
        const float* ob = outb + (size_t)g * 128 * kE;
        for (int mm = 0; mm < 128; ++mm)
            acc = fmaf(sc[g * 128 + mm], ob[(size_t)mm * kE + e], acc);
        part[g][e] = acc;
        __syncthreads();
        if (t < kE) {
            const float lo = (part[0][t] + part[1][t] + part[2][t] + part[3][t]) * inv;
            xbuf[t] = q_s[t] + lo;
        }
        __syncthreads();

        // --- new_q[e'] = sum_e xbuf[e] * w[e,e'] ---
        const float* w = (hop == 2) ? w_out : w_int;
        float acc2 = 0.0f;
        #pragma unroll 4
        for (int k = 0; k < 32; ++k) {
            const int ee = g * 32 + k;
            acc2 = fmaf(xbuf[ee], w[ee * kE + e], acc2);
        }
        part[g][e] = acc2;
        __syncthreads();
        if (t < kE) q_s[t] = part[0][t] + part[1][t] + part[2][t] + part[3][t];
        __syncthreads();
    }
    if (t < kE) x[b * kE + t] = fmaxf(q_s[t], 0.0f);
}

// -------------------------------------------------------------------------
// Kernel 3: out[b,v] = sum_e x[b,e] * w_final[e,v].
// Grid (V/256, 4): y-dim splits the e-loop into chunks of 32; partials
// accumulated with atomicAdd onto a zeroed d_out (for wave parallelism).
// -------------------------------------------------------------------------
__global__ __launch_bounds__(256) void final_mm_kernel(
    const float* __restrict__ x,    // [B,E]
    const float* __restrict__ wf,   // [E,V]
    float*       __restrict__ out)  // [B,V] (pre-zeroed)
{
    __shared__ float xs[kB * kE];
    const int t = threadIdx.x;
    for (int i = t; i < kB * kE; i += 256) xs[i] = x[i];
    __syncthreads();

    const int v  = blockIdx.x * 256 + t;
    const int e0 = blockIdx.y * 32;
    float acc[kB];
    #pragma unroll
    for (int b = 0; b < kB; ++b) acc[b] = 0.0f;
    for (int e = e0; e < e0 + 32; ++e) {
        const float w = wf[(size_t)e * kV + v];
        #pragma unroll
        for (int b = 0; b < kB; ++b) acc[b] = fmaf(xs[b * kE + e], w, acc[b]);
    }
    #pragma unroll
    for (int b = 0; b < kB; ++b) atomicAdd(&out[(size_t)b * kV + v], acc[b]);
}

// -------------------------------------------------------------------------
extern "C" void kernel_launch(void* const* d_in, const int* in_sizes, int n_in,
                              void* d_out, int out_size, void* d_ws, size_t ws_size,
                              hipStream_t stream)
{
    const int*   queries  = (const int*)  d_in[0];
    const int*   stories  = (const int*)  d_in[1];
    const float* q_bias   = (const float*)d_in[2];
    const float* st_bias  = (const float*)d_in[3];
    const float* mem_bias = (const float*)d_in[4];
    const float* out_bias = (const float*)d_in[5];
    const float* w_int    = (const float*)d_in[6];
    const float* w_out    = (const float*)d_in[7];
    const float* w_final  = (const float*)d_in[8];
    float* out = (float*)d_out;

    // Workspace layout: memory[B*M*E] | output[B*M*E] | x[B*E]  (~8.4 MB)
    float* memory = (float*)d_ws;
    float* output = memory + (size_t)kB * kM * kE;
    float* x      = output + (size_t)kB * kM * kE;

    hipMemsetAsync(d_out, 0, (size_t)out_size * sizeof(float), stream);

    embed_stories_kernel<<<dim3((kB * kM) / 2), dim3(256), 0, stream>>>(
        stories, st_bias, out_bias, mem_bias, memory, output);

    hops_kernel<<<dim3(kB), dim3(512), 0, stream>>>(
        queries, q_bias, memory, output, w_int, w_out, x);

    final_mm_kernel<<<dim3(kV / 256, 4), dim3(256), 0, stream>>>(x, w_final, out);
}